// Round 14
// baseline (3365.336 us; speedup 1.0000x reference)
//
#include <hip/hip_runtime.h>
#include <math.h>

#define T_TOTAL   1000
#define BATCH     256
#define NH        256
#define NIN       85
#define CHK       50            // steps per producer/consumer chunk
#define NCHUNK    (T_TOTAL/CHK) // 20
#define NPROD     224           // producer blocks (grid = 16 + 224 = 240 <= 256 CUs)
#define NTASK     (T_TOTAL*16)  // (t,R) tiles

static constexpr float SIGMA_C = 0.15811388300841897f;  // sqrt(2/0.2)*0.05
static constexpr float ALPHA_C = 0.2f;

using half4   = __attribute__((ext_vector_type(4))) _Float16;
using half8   = __attribute__((ext_vector_type(8))) _Float16;
using f32x4   = __attribute__((ext_vector_type(4))) float;

// workspace layout (ushort units)
#define GXEG_US   ((size_t)(T_TOTAL+1)*16*8*64*16)  // f16 gate preacts [t][R][w][lane][16] = 262MB
#define GXEE_US   ((size_t)(T_TOTAL+1)*16*8*64*8)   // f16 E tiles      [t][R][w][lane][8]  = 131MB
#define WPACK_US  (8u*6u*8u*64u*8u)                 // recurrent-weight B-fragments (f16 bits)
#define WXPACK_US (48u*3u*64u*8u)                   // x-weight B-fragments (K padded 85->96)

__device__ __forceinline__ unsigned short f2h(float f){
  _Float16 h = (_Float16)f;
  return __builtin_bit_cast(unsigned short, h);
}

// ---------------- k0: pack weights into MFMA B-fragment order (f16) ----------------
// wpack[w(8)][tile(6: r0,r1,u0,u1,c0,c1)][kt(8)][lane(64)][j(8)]
//   tau = 2w + (tile&1); value = W[k = kt*32 + (l>>4)*8 + j][col = 16*tau + (l&15)]
__global__ void k0_pack(const float* __restrict__ gk, const float* __restrict__ ck,
                        unsigned short* __restrict__ wpack, unsigned short* __restrict__ wxpack){
  int tid = blockIdx.x*256 + threadIdx.x;
  if (tid < (int)WPACK_US) {
    int j = tid & 7, l = (tid >> 3) & 63, kt = (tid >> 9) & 7, wt = tid >> 12;
    int w = wt / 6, tile = wt - 6*w;
    int lrow = l & 15, lquad = l >> 4;
    int k = kt*32 + lquad*8 + j;            // hidden index 0..255
    int tau = 2*w + (tile & 1);             // n-tile 0..15
    int kind = tile >> 1;                   // 0=r, 1=u, 2=c
    float v;
    if (kind == 0)      v = gk[(size_t)(85 + k)*512 + 16*tau + lrow];
    else if (kind == 1) v = gk[(size_t)(85 + k)*512 + 256 + 16*tau + lrow];
    else                v = ck[(size_t)(85 + k)*256 + 16*tau + lrow];
    wpack[tid] = f2h(v);
  } else if (tid < (int)(WPACK_US + WXPACK_US)) {
    int f = tid - (int)WPACK_US;
    int j = f & 7, l = (f >> 3) & 63, r = f >> 9;   // r = tau*3 + kt
    int kt = r % 3, tau = r / 3;
    int lrow = l & 15, lquad = l >> 4;
    int k = kt*32 + lquad*8 + j;            // x index, pad >=85 -> 0
    float v = 0.0f;
    if (k < NIN) {
      if (tau < 32) v = gk[(size_t)k*512 + 16*tau + lrow];
      else          v = ck[(size_t)k*256 + 16*(tau-32) + lrow];
    }
    wxpack[f] = f2h(v);
  }
}

// ---------------- fused kernel: 16 consumer blocks (the R10-champion scan) +
// ---------------- 224 producer blocks (k1's gxe tiles, t-ordered, chunk-flagged) ----
// Producer->consumer handoff: per-chunk counter. Producer: __syncthreads() (drains all
// waves' stores to L2) then one RELEASE/AGENT fetch_add (writes back XCD L2). Consumer:
// ACQUIRE/AGENT poll at chunk boundaries only; gxe lines are first-touch, no stale copy.
// Grid 240 <= 256 CUs: all blocks co-resident, no deadlock.
__global__ __launch_bounds__(512, 2) void k_fused(const float* __restrict__ hin,
                       const unsigned short* __restrict__ wpack,
                       const float* __restrict__ x, const float* __restrict__ nz,
                       const float* __restrict__ gb, const float* __restrict__ cb,
                       const unsigned short* __restrict__ wxpack,
                       unsigned short* __restrict__ gxeG, unsigned short* __restrict__ gxeE,
                       int* __restrict__ flags, float* __restrict__ out){
  __shared__ _Float16 hA[16][264];           // consumer: h f16 [row][n], stride 264
  __shared__ _Float16 rhA[16][264];          // consumer: r.*h f16
  __shared__ _Float16 xA[16][104];           // producer: x staging (96 padded + 8)

  int tid = threadIdx.x;
  int l = tid & 63, w = tid >> 6;
  int lrow = l & 15, lquad = l >> 4;

  if (blockIdx.x >= 16) {
    // ================= PRODUCER =================
    int pb = blockIdx.x - 16;
    const half8* wx8 = (const half8*)wxpack;
    for (int q = pb; q < NTASK; q += NPROD) {
      int t = q >> 4, R = q & 15;
      { // stage x row-block (512 threads: 32 per row)
        int r = tid >> 5, c0 = tid & 31;
        const float* xrow = x + ((size_t)t*BATCH + 16*R + r)*NIN;
        for (int c = c0; c < 96; c += 32)
          xA[r][c] = (_Float16)(c < NIN ? xrow[c] : 0.0f);
      }
      __syncthreads();
      const half8* xA8 = (const half8*)xA;   // row stride 13 half8
      half8 afr[3];
      #pragma unroll
      for (int kt = 0; kt < 3; ++kt)
        afr[kt] = xA8[lrow*13 + kt*4 + lquad];
      #pragma unroll
      for (int u = 0; u < 6; ++u) {
        int tau = w + 8*u;                   // 8 waves x 6 = 48 taus
        f32x4 acc;
        if (tau < 32) {
          float b = gb[16*tau + lrow];
          acc = (f32x4){b, b, b, b};
        } else {
          int nc = 16*(tau-32) + lrow;
          float b = cb[nc];
          #pragma unroll
          for (int i = 0; i < 4; ++i)
            acc[i] = fmaf(SIGMA_C, nz[((size_t)t*BATCH + 16*R + lquad*4 + i)*NH + nc], b);
        }
        #pragma unroll
        for (int kt = 0; kt < 3; ++kt)
          acc = __builtin_amdgcn_mfma_f32_16x16x32_f16(afr[kt], wx8[((size_t)tau*3 + kt)*64 + l], acc, 0, 0, 0);
        half4 o = {(_Float16)acc[0], (_Float16)acc[1], (_Float16)acc[2], (_Float16)acc[3]};
        if (tau < 32) {
          int kind = tau >> 4, w2 = (tau & 15) >> 1, p = tau & 1;
          *(half4*)(gxeG + ((((size_t)t*16 + R)*8 + w2)*64 + (size_t)l)*16 + kind*8 + p*4) = o;
        } else {
          int e = tau - 32, w2 = e >> 1, p = e & 1;
          *(half4*)(gxeE + ((((size_t)t*16 + R)*8 + w2)*64 + (size_t)l)*8 + p*4) = o;
        }
      }
      __syncthreads();   // drains every wave's stores (vmcnt 0) + xA reads done
      if (tid == 0)
        __hip_atomic_fetch_add(&flags[t / CHK], 1, __ATOMIC_RELEASE, __HIP_MEMORY_SCOPE_AGENT);
    }
    return;
  }

  // ================= CONSUMER (exact R10 champion body + chunk waits) =================
  int R = blockIdx.x;

  { // init hA
    int r = tid >> 5, c0 = (tid & 31)*8;
    const float* hrow = hin + ((size_t)(16*R + r))*NH + c0;
    #pragma unroll
    for (int i = 0; i < 8; ++i)
      hA[r][c0+i] = (_Float16)hrow[i];
  }
  float hreg[2][4];                          // h f32, lane-private
  #pragma unroll
  for (int p = 0; p < 2; ++p)
    #pragma unroll
    for (int i = 0; i < 4; ++i)
      hreg[p][i] = hin[(size_t)(16*R + lquad*4 + i)*NH + 32*w + 16*p + lrow];

  // resident weight fragments (192 regs; compiler splits arch/AGPR)
  half8 wf[6][8];
  const half8* wp8 = (const half8*)wpack;
  #pragma unroll
  for (int tile = 0; tile < 6; ++tile)
    #pragma unroll
    for (int kt = 0; kt < 8; ++kt)
      wf[tile][kt] = wp8[((w*6 + tile)*8 + kt)*64 + l];

  // gate / E streams: per-lane 32B (gates) + 16B (E) per step, f16
  const half8* gg  = (const half8*)gxeG + (((size_t)R*8 + w)*64 + (size_t)l)*2;
  const size_t gstepG = (size_t)16*8*64*2;
  const half8* gep = (const half8*)gxeE + (((size_t)R*8 + w)*64 + (size_t)l);
  const size_t estep = (size_t)16*8*64;

  // wait for chunk 0 before the first gate/E loads
  while (__hip_atomic_load(&flags[0], __ATOMIC_ACQUIRE, __HIP_MEMORY_SCOPE_AGENT) < CHK*16)
    __builtin_amdgcn_s_sleep(32);

  half8 g0 = gg[0], g1 = gg[1];  gg += gstepG;   // gates(0)
  half8 eh = gep[0];             gep += estep;   // E(0)
  __syncthreads();

  const half8* hA8  = (const half8*)hA;      // row stride 33 half8
  const half8* rhA8 = (const half8*)rhA;
  float* outp = out + ((size_t)(16*R + lquad*4))*NH + 32*w + lrow;

  for (int t = 0; t < T_TOTAL; ++t) {
    // chunk gate: all loads of chunk c data happen at/after step c*CHK-1's top
    if ((t % CHK) == CHK-1 && t != T_TOTAL-1) {
      int c = (t+1) / CHK;
      while (__hip_atomic_load(&flags[c], __ATOMIC_ACQUIRE, __HIP_MEMORY_SCOPE_AGENT) < CHK*16)
        __builtin_amdgcn_s_sleep(32);
    }
    // acc init from prefetched gates (lane-private, no LDS)
    f32x4 accr[2], accu[2];
    #pragma unroll
    for (int p = 0; p < 2; ++p)
      #pragma unroll
      for (int i = 0; i < 4; ++i){
        accr[p][i] = (float)g0[p*4 + i];
        accu[p][i] = (float)g1[p*4 + i];
      }
    // prefetch gates(t+1) (slack slab at t=999); ~full step covers HBM latency
    g0 = gg[0]; g1 = gg[1]; gg += gstepG;
    // phase A: h @ Wg_h  (tiles r0,r1,u0,u1)
    #pragma unroll
    for (int kt = 0; kt < 8; ++kt){
      half8 af = hA8[lrow*33 + kt*4 + lquad];
      #pragma unroll
      for (int p = 0; p < 2; ++p){
        accr[p] = __builtin_amdgcn_mfma_f32_16x16x32_f16(af, wf[p  ][kt], accr[p], 0, 0, 0);
        accu[p] = __builtin_amdgcn_mfma_f32_16x16x32_f16(af, wf[2+p][kt], accu[p], 0, 0, 0);
      }
    }
    // ew1: u-gates -> packed f16 aug; r-gates -> rhA
    half4 haug[2];
    #pragma unroll
    for (int p = 0; p < 2; ++p)
      #pragma unroll
      for (int i = 0; i < 4; ++i){
        float eu = __expf(-accu[p][i]);
        haug[p][i] = (_Float16)(ALPHA_C * __builtin_amdgcn_rcpf(1.0f + eu));
      }
    #pragma unroll
    for (int p = 0; p < 2; ++p){
      int ncol = 32*w + 16*p + lrow;
      #pragma unroll
      for (int i = 0; i < 4; ++i){
        float er = __expf(-accr[p][i]);
        float rg = __builtin_amdgcn_rcpf(1.0f + er);
        rhA[lquad*4+i][ncol] = (_Float16)(rg * hreg[p][i]);
      }
    }
    asm volatile("s_waitcnt lgkmcnt(0)\n\ts_barrier" ::: "memory");  // rhA visible
    // phase B: (r.*h) @ Wc_h  (tiles c0,c1)
    f32x4 accB[2];
    accB[0] = (f32x4){0.f,0.f,0.f,0.f};
    accB[1] = (f32x4){0.f,0.f,0.f,0.f};
    #pragma unroll
    for (int kt = 0; kt < 8; ++kt){
      half8 af = rhA8[lrow*33 + kt*4 + lquad];
      #pragma unroll
      for (int p = 0; p < 2; ++p)
        accB[p] = __builtin_amdgcn_mfma_f32_16x16x32_f16(af, wf[4+p][kt], accB[p], 0, 0, 0);
    }
    // ew2: cand -> tanh -> leaky update; publish new h; 8 out stores (never drained)
    #pragma unroll
    for (int p = 0; p < 2; ++p){
      int ncol = 32*w + 16*p + lrow;
      #pragma unroll
      for (int i = 0; i < 4; ++i){
        float cand = accB[p][i] + (float)eh[p*4 + i];
        float e2 = __expf(2.0f*cand);
        float c  = (e2 - 1.0f)*__builtin_amdgcn_rcpf(e2 + 1.0f);
        float hold = hreg[p][i];
        float hnew = fmaf((float)haug[p][i], c - hold, hold);
        hreg[p][i] = hnew;
        hA[lquad*4+i][ncol] = (_Float16)hnew;
        outp[(size_t)i*NH + (size_t)p*16] = hnew;
      }
    }
    outp += (size_t)BATCH*NH;
    // prefetch E(t+1) after last use of eh
    eh = gep[0]; gep += estep;
    asm volatile("s_waitcnt lgkmcnt(0)\n\ts_barrier" ::: "memory");  // hA visible
  }
}

extern "C" void kernel_launch(void* const* d_in, const int* in_sizes, int n_in,
                              void* d_out, int out_size, void* d_ws, size_t ws_size,
                              hipStream_t stream) {
  (void)in_sizes; (void)n_in; (void)out_size; (void)ws_size;
  const float* x  = (const float*)d_in[0];
  const float* h0 = (const float*)d_in[1];
  const float* gk = (const float*)d_in[2];
  const float* gb = (const float*)d_in[3];
  const float* ck = (const float*)d_in[4];
  const float* cb = (const float*)d_in[5];
  const float* nz = (const float*)d_in[6];
  float* out = (float*)d_out;

  unsigned short* gxeG   = (unsigned short*)d_ws;           // 262MB f16 gates
  unsigned short* gxeE   = gxeG + GXEG_US;                  // 131MB f16 E
  unsigned short* wpack  = gxeE + GXEE_US;
  unsigned short* wxpack = wpack + WPACK_US;
  int*            flags  = (int*)(wxpack + WXPACK_US);      // NCHUNK counters

  hipMemsetAsync(flags, 0, NCHUNK*sizeof(int), stream);
  k0_pack<<<1056, 256, 0, stream>>>(gk, ck, wpack, wxpack);
  k_fused<<<16 + NPROD, 512, 0, stream>>>(h0, wpack, x, nz, gb, cb, wxpack,
                                          gxeG, gxeE, flags, out);
}

// Round 15
// 2487.791 us; speedup vs baseline: 1.3527x; 1.3527x over previous
//
#include <hip/hip_runtime.h>
#include <math.h>

#define T_TOTAL   1000
#define BATCH     256
#define NH        256
#define NIN       85

static constexpr float SIGMA_C = 0.15811388300841897f;  // sqrt(2/0.2)*0.05
static constexpr float ALPHA_C = 0.2f;
static constexpr float NLOG2E  = -1.4426950408889634f;  // gate preact scale (exp2 folding)
static constexpr float P2LOG2E =  2.8853900817779268f;  // cand preact scale (2*log2e)

using half4   = __attribute__((ext_vector_type(4))) _Float16;
using half8   = __attribute__((ext_vector_type(8))) _Float16;
using f32x4   = __attribute__((ext_vector_type(4))) float;

// workspace layout (ushort units)
#define GXEG_US   ((size_t)(T_TOTAL+1)*16*8*64*16)  // f16 gate preacts [t][R][w][lane][16] = 262MB
#define GXEE_US   ((size_t)(T_TOTAL+1)*16*8*64*8)   // f16 E tiles      [t][R][w][lane][8]  = 131MB
#define WPACK_US  (8u*6u*8u*64u*8u)                 // recurrent-weight B-fragments (f16 bits)
#define WXPACK_US (48u*3u*64u*8u)                   // x-weight B-fragments (K padded 85->96)

__device__ __forceinline__ unsigned short f2h(float f){
  _Float16 h = (_Float16)f;
  return __builtin_bit_cast(unsigned short, h);
}

// ---------------- k0: pack weights into MFMA B-fragment order (f16) ----------------
// wpack[w(8)][tile(6: r0,r1,u0,u1,c0,c1)][kt(8)][lane(64)][j(8)]
//   tau = 2w + (tile&1); value = W[k = kt*32 + (l>>4)*8 + j][col = 16*tau + (l&15)]
// exp2 folding: r,u tiles scaled by -log2(e); c tiles by +2*log2(e). k1 scales its
// gate/E outputs identically, so k2's v_exp_f32 computes exp/tanh exactly.
__global__ void k0_pack(const float* __restrict__ gk, const float* __restrict__ ck,
                        unsigned short* __restrict__ wpack, unsigned short* __restrict__ wxpack){
  int tid = blockIdx.x*256 + threadIdx.x;
  if (tid < (int)WPACK_US) {
    int j = tid & 7, l = (tid >> 3) & 63, kt = (tid >> 9) & 7, wt = tid >> 12;
    int w = wt / 6, tile = wt - 6*w;
    int lrow = l & 15, lquad = l >> 4;
    int k = kt*32 + lquad*8 + j;            // hidden index 0..255
    int tau = 2*w + (tile & 1);             // n-tile 0..15
    int kind = tile >> 1;                   // 0=r, 1=u, 2=c
    float v;
    if (kind == 0)      v = NLOG2E  * gk[(size_t)(85 + k)*512 + 16*tau + lrow];
    else if (kind == 1) v = NLOG2E  * gk[(size_t)(85 + k)*512 + 256 + 16*tau + lrow];
    else                v = P2LOG2E * ck[(size_t)(85 + k)*256 + 16*tau + lrow];
    wpack[tid] = f2h(v);
  } else if (tid < (int)(WPACK_US + WXPACK_US)) {
    int f = tid - (int)WPACK_US;
    int j = f & 7, l = (f >> 3) & 63, r = f >> 9;   // r = tau*3 + kt
    int kt = r % 3, tau = r / 3;
    int lrow = l & 15, lquad = l >> 4;
    int k = kt*32 + lquad*8 + j;            // x index (unscaled), pad >=85 -> 0
    float v = 0.0f;
    if (k < NIN) {
      if (tau < 32) v = gk[(size_t)k*512 + 16*tau + lrow];
      else          v = ck[(size_t)k*256 + 16*(tau-32) + lrow];
    }
    wxpack[f] = f2h(v);
  }
}

// ---------------- k1: gxe precompute, 4 timesteps per block ----------------
// gates (tau<32): scaled by -log2e -> f16 gxeG[t][R][w][lane][kind*8 + p*4 + i]
// E (tau>=32):    scaled by 2log2e -> f16 gxeE[t][R][e>>1][lane][(e&1)*4 + i]
__global__ __launch_bounds__(256) void k1_gxe(const float* __restrict__ x, const float* __restrict__ nz,
                       const float* __restrict__ gb, const float* __restrict__ cb,
                       const unsigned short* __restrict__ wxpack,
                       unsigned short* __restrict__ gxeG, unsigned short* __restrict__ gxeE){
  int R  = blockIdx.x;
  int t0 = blockIdx.y * 4;
  int tid = threadIdx.x;
  __shared__ _Float16 xA[16][104];           // 96 K (padded) + 8 pad
  int l = tid & 63, wv = tid >> 6;
  int lrow = l & 15, lquad = l >> 4;
  const half8* xA8 = (const half8*)xA;       // row stride 104 f16 = 13 half8
  const half8* wx8 = (const half8*)wxpack;

  for (int tt = 0; tt < 4; ++tt) {
    int t = t0 + tt;
    {
      int r = tid >> 4, c0 = tid & 15;
      const float* xrow = x + ((size_t)t*BATCH + 16*R + r)*NIN;
      for (int c = c0; c < 96; c += 16)
        xA[r][c] = (_Float16)(c < NIN ? xrow[c] : 0.0f);
    }
    __syncthreads();
    half8 afr[3];
    #pragma unroll
    for (int kt = 0; kt < 3; ++kt)
      afr[kt] = xA8[lrow*13 + kt*4 + lquad];
    for (int u = 0; u < 12; ++u) {
      int tau = wv + 4*u;                    // balanced: each wave gets 4 cand tiles
      f32x4 acc;
      if (tau < 32) {
        float b = gb[16*tau + lrow];
        acc = (f32x4){b, b, b, b};
      } else {
        int nc = 16*(tau-32) + lrow;
        float b = cb[nc];
        #pragma unroll
        for (int i = 0; i < 4; ++i)
          acc[i] = fmaf(SIGMA_C, nz[((size_t)t*BATCH + 16*R + lquad*4 + i)*NH + nc], b);
      }
      #pragma unroll
      for (int kt = 0; kt < 3; ++kt)
        acc = __builtin_amdgcn_mfma_f32_16x16x32_f16(afr[kt], wx8[((size_t)tau*3 + kt)*64 + l], acc, 0, 0, 0);
      float sc = (tau < 32) ? NLOG2E : P2LOG2E;
      half4 o = {(_Float16)(sc*acc[0]), (_Float16)(sc*acc[1]),
                 (_Float16)(sc*acc[2]), (_Float16)(sc*acc[3])};
      if (tau < 32) {
        int kind = tau >> 4, w2 = (tau & 15) >> 1, p = tau & 1;
        *(half4*)(gxeG + ((((size_t)t*16 + R)*8 + w2)*64 + (size_t)l)*16 + kind*8 + p*4) = o;
      } else {
        int e = tau - 32, w2 = e >> 1, p = e & 1;
        *(half4*)(gxeE + ((((size_t)t*16 + R)*8 + w2)*64 + (size_t)l)*8 + p*4) = o;
      }
    }
    __syncthreads();   // xA reads done before next tt restages
  }
}

// ---------------- k2: ONE persistent recurrent scan over all 1000 steps ----------------
// 16 WGs x 8 waves (2 waves/SIMD). WG R owns rows [16R,16R+16); wave w owns cols [32w,32w+32).
// cand = cx + (r .* h) @ Wc_h + sigma*n  (r applied BEFORE the matmul).
// Exact R10 champion + (1) exp2-folded preacts: sigmoid = rcp(1+exp2(acc')) with acc'
// pre-scaled by -log2e in k0/k1 (saves the v_mul per __expf); tanh via exp2 of the
// 2log2e-scaled cand. (2) out-stores deferred past the end-of-step barrier (issue
// under next step's MFMA shadow). Gate/E streams HBM->VGPR f16 double-buffered;
// 2 hand-rolled barriers/step; stores never drained in-loop.
__global__ __launch_bounds__(512, 2) void k2_rec(const float* __restrict__ hin,
                       const unsigned short* __restrict__ wpack,
                       const unsigned short* __restrict__ gG,
                       const unsigned short* __restrict__ gE,
                       float* __restrict__ out){
  int R = blockIdx.x;
  int tid = threadIdx.x;
  int l = tid & 63, w = tid >> 6;
  int lrow = l & 15, lquad = l >> 4;

  __shared__ _Float16 hA[16][264];           // h f16  [row][n], stride 264
  __shared__ _Float16 rhA[16][264];          // r.*h f16, same layout

  { // init hA
    int r = tid >> 5, c0 = (tid & 31)*8;
    const float* hrow = hin + ((size_t)(16*R + r))*NH + c0;
    #pragma unroll
    for (int i = 0; i < 8; ++i)
      hA[r][c0+i] = (_Float16)hrow[i];
  }
  float hreg[2][4];                          // h f32, lane-private (rows lquad*4+i, cols 32w+16p+lrow)
  #pragma unroll
  for (int p = 0; p < 2; ++p)
    #pragma unroll
    for (int i = 0; i < 4; ++i)
      hreg[p][i] = hin[(size_t)(16*R + lquad*4 + i)*NH + 32*w + 16*p + lrow];

  // resident weight fragments (192 regs; compiler splits arch/AGPR — MFMA reads AGPR srcB directly)
  half8 wf[6][8];
  const half8* wp8 = (const half8*)wpack;
  #pragma unroll
  for (int tile = 0; tile < 6; ++tile)
    #pragma unroll
    for (int kt = 0; kt < 8; ++kt)
      wf[tile][kt] = wp8[((w*6 + tile)*8 + kt)*64 + l];

  // gate / E streams: per-lane 32B (gates) + 16B (E) per step, f16
  const half8* gg  = (const half8*)gG + (((size_t)R*8 + w)*64 + (size_t)l)*2;
  const size_t gstepG = (size_t)16*8*64*2;   // half8 units per time step
  const half8* gep = (const half8*)gE + (((size_t)R*8 + w)*64 + (size_t)l);
  const size_t estep = (size_t)16*8*64;      // half8 units per time step

  half8 g0 = gg[0], g1 = gg[1];  gg += gstepG;   // gates(0): [r p0..p1 | u p0..p1]
  half8 eh = gep[0];             gep += estep;   // E(0)
  __syncthreads();

  const half8* hA8  = (const half8*)hA;      // row stride 33 half8
  const half8* rhA8 = (const half8*)rhA;
  float* outp = out + ((size_t)(16*R + lquad*4))*NH + 32*w + lrow;

  float hnv[2][4];                           // deferred out-store values
  #pragma unroll
  for (int p = 0; p < 2; ++p)
    #pragma unroll
    for (int i = 0; i < 4; ++i) hnv[p][i] = 0.0f;

  for (int t = 0; t < T_TOTAL; ++t) {
    // acc init from prefetched gates (lane-private, no LDS)
    f32x4 accr[2], accu[2];
    #pragma unroll
    for (int p = 0; p < 2; ++p)
      #pragma unroll
      for (int i = 0; i < 4; ++i){
        accr[p][i] = (float)g0[p*4 + i];
        accu[p][i] = (float)g1[p*4 + i];
      }
    // prefetch gates(t+1) (slack slab at t=999); ~full step covers HBM latency
    g0 = gg[0]; g1 = gg[1]; gg += gstepG;
    // phase A: h @ Wg_h  (tiles r0,r1,u0,u1)
    #pragma unroll
    for (int kt = 0; kt < 8; ++kt){
      half8 af = hA8[lrow*33 + kt*4 + lquad];
      #pragma unroll
      for (int p = 0; p < 2; ++p){
        accr[p] = __builtin_amdgcn_mfma_f32_16x16x32_f16(af, wf[p  ][kt], accr[p], 0, 0, 0);
        accu[p] = __builtin_amdgcn_mfma_f32_16x16x32_f16(af, wf[2+p][kt], accu[p], 0, 0, 0);
      }
    }
    // ew1: u-gates -> packed f16 aug; r-gates -> rhA   (preacts exp2-scaled)
    half4 haug[2];
    #pragma unroll
    for (int p = 0; p < 2; ++p)
      #pragma unroll
      for (int i = 0; i < 4; ++i){
        float eu = __builtin_exp2f(accu[p][i]);
        haug[p][i] = (_Float16)(ALPHA_C * __builtin_amdgcn_rcpf(1.0f + eu));
      }
    #pragma unroll
    for (int p = 0; p < 2; ++p){
      int ncol = 32*w + 16*p + lrow;
      #pragma unroll
      for (int i = 0; i < 4; ++i){
        float er = __builtin_exp2f(accr[p][i]);
        float rg = __builtin_amdgcn_rcpf(1.0f + er);
        rhA[lquad*4+i][ncol] = (_Float16)(rg * hreg[p][i]);
      }
    }
    asm volatile("s_waitcnt lgkmcnt(0)\n\ts_barrier" ::: "memory");  // rhA visible
    // phase B: (r.*h) @ Wc_h  (tiles c0,c1; 2log2e-scaled)
    f32x4 accB[2];
    accB[0] = (f32x4){0.f,0.f,0.f,0.f};
    accB[1] = (f32x4){0.f,0.f,0.f,0.f};
    #pragma unroll
    for (int kt = 0; kt < 8; ++kt){
      half8 af = rhA8[lrow*33 + kt*4 + lquad];
      #pragma unroll
      for (int p = 0; p < 2; ++p)
        accB[p] = __builtin_amdgcn_mfma_f32_16x16x32_f16(af, wf[4+p][kt], accB[p], 0, 0, 0);
    }
    // ew2: tanh via exp2 -> leaky update; publish new h to LDS; out-stores DEFERRED
    #pragma unroll
    for (int p = 0; p < 2; ++p){
      int ncol = 32*w + 16*p + lrow;
      #pragma unroll
      for (int i = 0; i < 4; ++i){
        float e2 = __builtin_exp2f(accB[p][i] + (float)eh[p*4 + i]);
        float c  = fmaf(-2.0f, __builtin_amdgcn_rcpf(e2 + 1.0f), 1.0f);
        float hold = hreg[p][i];
        float hnew = fmaf((float)haug[p][i], c - hold, hold);
        hreg[p][i] = hnew;
        hnv[p][i] = hnew;
        hA[lquad*4+i][ncol] = (_Float16)hnew;
      }
    }
    // prefetch E(t+1) after last use of eh
    eh = gep[0]; gep += estep;
    asm volatile("s_waitcnt lgkmcnt(0)\n\ts_barrier" ::: "memory");  // hA visible
    // deferred out stores: issue under next step's phase A (no waits attached)
    #pragma unroll
    for (int p = 0; p < 2; ++p)
      #pragma unroll
      for (int i = 0; i < 4; ++i)
        outp[(size_t)i*NH + (size_t)p*16] = hnv[p][i];
    outp += (size_t)BATCH*NH;
  }
}

extern "C" void kernel_launch(void* const* d_in, const int* in_sizes, int n_in,
                              void* d_out, int out_size, void* d_ws, size_t ws_size,
                              hipStream_t stream) {
  (void)in_sizes; (void)n_in; (void)out_size; (void)ws_size;
  const float* x  = (const float*)d_in[0];
  const float* h0 = (const float*)d_in[1];
  const float* gk = (const float*)d_in[2];
  const float* gb = (const float*)d_in[3];
  const float* ck = (const float*)d_in[4];
  const float* cb = (const float*)d_in[5];
  const float* nz = (const float*)d_in[6];
  float* out = (float*)d_out;

  unsigned short* gxeG   = (unsigned short*)d_ws;           // 262MB f16 gates
  unsigned short* gxeE   = gxeG + GXEG_US;                  // 131MB f16 E
  unsigned short* wpack  = gxeE + GXEE_US;
  unsigned short* wxpack = wpack + WPACK_US;

  k0_pack<<<1056, 256, 0, stream>>>(gk, ck, wpack, wxpack);
  k1_gxe<<<dim3(16, T_TOTAL/4), 256, 0, stream>>>(x, nz, gb, cb, wxpack, gxeG, gxeE);
  k2_rec<<<16, 512, 0, stream>>>(h0, wpack, gxeG, gxeE, out);
}

// Round 16
// 2437.751 us; speedup vs baseline: 1.3805x; 1.0205x over previous
//
#include <hip/hip_runtime.h>
#include <math.h>

#define T_TOTAL   1000
#define BATCH     256
#define NH        256
#define NIN       85

static constexpr float SIGMA_C = 0.15811388300841897f;  // sqrt(2/0.2)*0.05
static constexpr float ALPHA_C = 0.2f;
static constexpr float NLOG2E  = -1.4426950408889634f;  // gate preact scale (exp2 folding)
static constexpr float P2LOG2E =  2.8853900817779268f;  // cand preact scale (2*log2e)

using half4   = __attribute__((ext_vector_type(4))) _Float16;
using half8   = __attribute__((ext_vector_type(8))) _Float16;
using f32x4   = __attribute__((ext_vector_type(4))) float;

// workspace layout (ushort units)
#define GXEG_US   ((size_t)(T_TOTAL+1)*16*8*64*16)  // f16 gate preacts [t][R][w][lane][16] = 262MB
#define GXEE_US   ((size_t)(T_TOTAL+1)*16*8*64*8)   // f16 E tiles      [t][R][w][lane][8]  = 131MB
#define WPACK_US  (8u*6u*8u*64u*8u)                 // recurrent-weight B-fragments (f16 bits)
#define WXPACK_US (48u*3u*64u*8u)                   // x-weight B-fragments (K padded 85->96)

__device__ __forceinline__ unsigned short f2h(float f){
  _Float16 h = (_Float16)f;
  return __builtin_bit_cast(unsigned short, h);
}

// ---------------- k0: pack weights into MFMA B-fragment order (f16) ----------------
// wpack[w(8)][tile(6: r0,r1,u0,u1,c0,c1)][kt(8)][lane(64)][j(8)]
//   tau = 2w + (tile&1); value = W[k = kt*32 + (l>>4)*8 + j][col = 16*tau + (l&15)]
// exp2 folding: r,u tiles scaled by -log2(e); c tiles by +2*log2(e). k1 scales its
// gate/E outputs identically, so k2's v_exp_f32 (exp2) computes sigmoid/tanh exactly.
__global__ void k0_pack(const float* __restrict__ gk, const float* __restrict__ ck,
                        unsigned short* __restrict__ wpack, unsigned short* __restrict__ wxpack){
  int tid = blockIdx.x*256 + threadIdx.x;
  if (tid < (int)WPACK_US) {
    int j = tid & 7, l = (tid >> 3) & 63, kt = (tid >> 9) & 7, wt = tid >> 12;
    int w = wt / 6, tile = wt - 6*w;
    int lrow = l & 15, lquad = l >> 4;
    int k = kt*32 + lquad*8 + j;            // hidden index 0..255
    int tau = 2*w + (tile & 1);             // n-tile 0..15
    int kind = tile >> 1;                   // 0=r, 1=u, 2=c
    float v;
    if (kind == 0)      v = NLOG2E  * gk[(size_t)(85 + k)*512 + 16*tau + lrow];
    else if (kind == 1) v = NLOG2E  * gk[(size_t)(85 + k)*512 + 256 + 16*tau + lrow];
    else                v = P2LOG2E * ck[(size_t)(85 + k)*256 + 16*tau + lrow];
    wpack[tid] = f2h(v);
  } else if (tid < (int)(WPACK_US + WXPACK_US)) {
    int f = tid - (int)WPACK_US;
    int j = f & 7, l = (f >> 3) & 63, r = f >> 9;   // r = tau*3 + kt
    int kt = r % 3, tau = r / 3;
    int lrow = l & 15, lquad = l >> 4;
    int k = kt*32 + lquad*8 + j;            // x index (unscaled), pad >=85 -> 0
    float v = 0.0f;
    if (k < NIN) {
      if (tau < 32) v = gk[(size_t)k*512 + 16*tau + lrow];
      else          v = ck[(size_t)k*256 + 16*(tau-32) + lrow];
    }
    wxpack[f] = f2h(v);
  }
}

// ---------------- k1: gxe precompute, 4 timesteps per block ----------------
// gates (tau<32): scaled by -log2e -> f16 gxeG[t][R][w][lane][kind*8 + p*4 + i]
// E (tau>=32):    scaled by 2log2e -> f16 gxeE[t][R][e>>1][lane][(e&1)*4 + i]
__global__ __launch_bounds__(256) void k1_gxe(const float* __restrict__ x, const float* __restrict__ nz,
                       const float* __restrict__ gb, const float* __restrict__ cb,
                       const unsigned short* __restrict__ wxpack,
                       unsigned short* __restrict__ gxeG, unsigned short* __restrict__ gxeE){
  int R  = blockIdx.x;
  int t0 = blockIdx.y * 4;
  int tid = threadIdx.x;
  __shared__ _Float16 xA[16][104];           // 96 K (padded) + 8 pad
  int l = tid & 63, wv = tid >> 6;
  int lrow = l & 15, lquad = l >> 4;
  const half8* xA8 = (const half8*)xA;       // row stride 104 f16 = 13 half8
  const half8* wx8 = (const half8*)wxpack;

  for (int tt = 0; tt < 4; ++tt) {
    int t = t0 + tt;
    {
      int r = tid >> 4, c0 = tid & 15;
      const float* xrow = x + ((size_t)t*BATCH + 16*R + r)*NIN;
      for (int c = c0; c < 96; c += 16)
        xA[r][c] = (_Float16)(c < NIN ? xrow[c] : 0.0f);
    }
    __syncthreads();
    half8 afr[3];
    #pragma unroll
    for (int kt = 0; kt < 3; ++kt)
      afr[kt] = xA8[lrow*13 + kt*4 + lquad];
    for (int u = 0; u < 12; ++u) {
      int tau = wv + 4*u;                    // balanced: each wave gets 4 cand tiles
      f32x4 acc;
      if (tau < 32) {
        float b = gb[16*tau + lrow];
        acc = (f32x4){b, b, b, b};
      } else {
        int nc = 16*(tau-32) + lrow;
        float b = cb[nc];
        #pragma unroll
        for (int i = 0; i < 4; ++i)
          acc[i] = fmaf(SIGMA_C, nz[((size_t)t*BATCH + 16*R + lquad*4 + i)*NH + nc], b);
      }
      #pragma unroll
      for (int kt = 0; kt < 3; ++kt)
        acc = __builtin_amdgcn_mfma_f32_16x16x32_f16(afr[kt], wx8[((size_t)tau*3 + kt)*64 + l], acc, 0, 0, 0);
      float sc = (tau < 32) ? NLOG2E : P2LOG2E;
      half4 o = {(_Float16)(sc*acc[0]), (_Float16)(sc*acc[1]),
                 (_Float16)(sc*acc[2]), (_Float16)(sc*acc[3])};
      if (tau < 32) {
        int kind = tau >> 4, w2 = (tau & 15) >> 1, p = tau & 1;
        *(half4*)(gxeG + ((((size_t)t*16 + R)*8 + w2)*64 + (size_t)l)*16 + kind*8 + p*4) = o;
      } else {
        int e = tau - 32, w2 = e >> 1, p = e & 1;
        *(half4*)(gxeE + ((((size_t)t*16 + R)*8 + w2)*64 + (size_t)l)*8 + p*4) = o;
      }
    }
    __syncthreads();   // xA reads done before next tt restages
  }
}

// ---------------- k2: ONE persistent recurrent scan over all 1000 steps ----------------
// 16 WGs x 8 waves (2 waves/SIMD). WG R owns rows [16R,16R+16); wave w owns cols [32w,32w+32).
// cand = cx + (r .* h) @ Wc_h + sigma*n  (r applied BEFORE the matmul).
// EXACT R10 champion body (store position, barrier placement, live ranges unchanged).
// Only delta: preacts arrive exp2-pre-scaled (k0/k1), so sigmoid/tanh use bare
// __builtin_exp2f — 24 fewer v_mul per wave-step, no live-range growth (R15 lesson:
// extending ANY live range across the barrier forces spills under the 128-reg cap).
__global__ __launch_bounds__(512, 2) void k2_rec(const float* __restrict__ hin,
                       const unsigned short* __restrict__ wpack,
                       const unsigned short* __restrict__ gG,
                       const unsigned short* __restrict__ gE,
                       float* __restrict__ out){
  int R = blockIdx.x;
  int tid = threadIdx.x;
  int l = tid & 63, w = tid >> 6;
  int lrow = l & 15, lquad = l >> 4;

  __shared__ _Float16 hA[16][264];           // h f16  [row][n], stride 264
  __shared__ _Float16 rhA[16][264];          // r.*h f16, same layout

  { // init hA
    int r = tid >> 5, c0 = (tid & 31)*8;
    const float* hrow = hin + ((size_t)(16*R + r))*NH + c0;
    #pragma unroll
    for (int i = 0; i < 8; ++i)
      hA[r][c0+i] = (_Float16)hrow[i];
  }
  float hreg[2][4];                          // h f32, lane-private (rows lquad*4+i, cols 32w+16p+lrow)
  #pragma unroll
  for (int p = 0; p < 2; ++p)
    #pragma unroll
    for (int i = 0; i < 4; ++i)
      hreg[p][i] = hin[(size_t)(16*R + lquad*4 + i)*NH + 32*w + 16*p + lrow];

  // resident weight fragments (192 regs; compiler splits arch/AGPR — MFMA reads AGPR srcB directly)
  half8 wf[6][8];
  const half8* wp8 = (const half8*)wpack;
  #pragma unroll
  for (int tile = 0; tile < 6; ++tile)
    #pragma unroll
    for (int kt = 0; kt < 8; ++kt)
      wf[tile][kt] = wp8[((w*6 + tile)*8 + kt)*64 + l];

  // gate / E streams: per-lane 32B (gates) + 16B (E) per step, f16
  const half8* gg  = (const half8*)gG + (((size_t)R*8 + w)*64 + (size_t)l)*2;
  const size_t gstepG = (size_t)16*8*64*2;   // half8 units per time step
  const half8* gep = (const half8*)gE + (((size_t)R*8 + w)*64 + (size_t)l);
  const size_t estep = (size_t)16*8*64;      // half8 units per time step

  half8 g0 = gg[0], g1 = gg[1];  gg += gstepG;   // gates(0): [r p0..p1 | u p0..p1]
  half8 eh = gep[0];             gep += estep;   // E(0)
  __syncthreads();

  const half8* hA8  = (const half8*)hA;      // row stride 33 half8
  const half8* rhA8 = (const half8*)rhA;
  float* outp = out + ((size_t)(16*R + lquad*4))*NH + 32*w + lrow;

  for (int t = 0; t < T_TOTAL; ++t) {
    // acc init from prefetched gates (lane-private, no LDS)
    f32x4 accr[2], accu[2];
    #pragma unroll
    for (int p = 0; p < 2; ++p)
      #pragma unroll
      for (int i = 0; i < 4; ++i){
        accr[p][i] = (float)g0[p*4 + i];
        accu[p][i] = (float)g1[p*4 + i];
      }
    // prefetch gates(t+1) (slack slab at t=999); ~full step covers HBM latency
    g0 = gg[0]; g1 = gg[1]; gg += gstepG;
    // phase A: h @ Wg_h  (tiles r0,r1,u0,u1)
    #pragma unroll
    for (int kt = 0; kt < 8; ++kt){
      half8 af = hA8[lrow*33 + kt*4 + lquad];
      #pragma unroll
      for (int p = 0; p < 2; ++p){
        accr[p] = __builtin_amdgcn_mfma_f32_16x16x32_f16(af, wf[p  ][kt], accr[p], 0, 0, 0);
        accu[p] = __builtin_amdgcn_mfma_f32_16x16x32_f16(af, wf[2+p][kt], accu[p], 0, 0, 0);
      }
    }
    // ew1: u-gates -> packed f16 aug; r-gates -> rhA   (preacts exp2-pre-scaled)
    half4 haug[2];
    #pragma unroll
    for (int p = 0; p < 2; ++p)
      #pragma unroll
      for (int i = 0; i < 4; ++i){
        float eu = __builtin_exp2f(accu[p][i]);
        haug[p][i] = (_Float16)(ALPHA_C * __builtin_amdgcn_rcpf(1.0f + eu));
      }
    #pragma unroll
    for (int p = 0; p < 2; ++p){
      int ncol = 32*w + 16*p + lrow;
      #pragma unroll
      for (int i = 0; i < 4; ++i){
        float er = __builtin_exp2f(accr[p][i]);
        float rg = __builtin_amdgcn_rcpf(1.0f + er);
        rhA[lquad*4+i][ncol] = (_Float16)(rg * hreg[p][i]);
      }
    }
    asm volatile("s_waitcnt lgkmcnt(0)\n\ts_barrier" ::: "memory");  // rhA visible
    // phase B: (r.*h) @ Wc_h  (tiles c0,c1; 2log2e-pre-scaled)
    f32x4 accB[2];
    accB[0] = (f32x4){0.f,0.f,0.f,0.f};
    accB[1] = (f32x4){0.f,0.f,0.f,0.f};
    #pragma unroll
    for (int kt = 0; kt < 8; ++kt){
      half8 af = rhA8[lrow*33 + kt*4 + lquad];
      #pragma unroll
      for (int p = 0; p < 2; ++p)
        accB[p] = __builtin_amdgcn_mfma_f32_16x16x32_f16(af, wf[4+p][kt], accB[p], 0, 0, 0);
    }
    // ew2: tanh via exp2 -> leaky update; publish new h; 8 out stores INLINE (R10 position)
    #pragma unroll
    for (int p = 0; p < 2; ++p){
      int ncol = 32*w + 16*p + lrow;
      #pragma unroll
      for (int i = 0; i < 4; ++i){
        float e2 = __builtin_exp2f(accB[p][i] + (float)eh[p*4 + i]);
        float c  = fmaf(-2.0f, __builtin_amdgcn_rcpf(e2 + 1.0f), 1.0f);
        float hold = hreg[p][i];
        float hnew = fmaf((float)haug[p][i], c - hold, hold);
        hreg[p][i] = hnew;
        hA[lquad*4+i][ncol] = (_Float16)hnew;
        outp[(size_t)i*NH + (size_t)p*16] = hnew;
      }
    }
    outp += (size_t)BATCH*NH;
    // prefetch E(t+1) after last use of eh
    eh = gep[0]; gep += estep;
    asm volatile("s_waitcnt lgkmcnt(0)\n\ts_barrier" ::: "memory");  // hA visible
  }
}

extern "C" void kernel_launch(void* const* d_in, const int* in_sizes, int n_in,
                              void* d_out, int out_size, void* d_ws, size_t ws_size,
                              hipStream_t stream) {
  (void)in_sizes; (void)n_in; (void)out_size; (void)ws_size;
  const float* x  = (const float*)d_in[0];
  const float* h0 = (const float*)d_in[1];
  const float* gk = (const float*)d_in[2];
  const float* gb = (const float*)d_in[3];
  const float* ck = (const float*)d_in[4];
  const float* cb = (const float*)d_in[5];
  const float* nz = (const float*)d_in[6];
  float* out = (float*)d_out;

  unsigned short* gxeG   = (unsigned short*)d_ws;           // 262MB f16 gates
  unsigned short* gxeE   = gxeG + GXEG_US;                  // 131MB f16 E
  unsigned short* wpack  = gxeE + GXEE_US;
  unsigned short* wxpack = wpack + WPACK_US;

  k0_pack<<<1056, 256, 0, stream>>>(gk, ck, wpack, wxpack);
  k1_gxe<<<dim3(16, T_TOTAL/4), 256, 0, stream>>>(x, nz, gb, cb, wxpack, gxeG, gxeE);
  k2_rec<<<16, 512, 0, stream>>>(h0, wpack, gxeG, gxeE, out);
}

// Round 17
// 2128.171 us; speedup vs baseline: 1.5813x; 1.1455x over previous
//
#include <hip/hip_runtime.h>
#include <math.h>

#define T_TOTAL   1000
#define BATCH     256
#define NH        256
#define NIN       85

static constexpr float SIGMA_C = 0.15811388300841897f;  // sqrt(2/0.2)*0.05
static constexpr float ALPHA_C = 0.2f;

using half4   = __attribute__((ext_vector_type(4))) _Float16;
using half8   = __attribute__((ext_vector_type(8))) _Float16;
using f32x4   = __attribute__((ext_vector_type(4))) float;

// workspace layout (ushort units)
#define GXEG_US   ((size_t)(T_TOTAL+1)*16*8*64*16)  // f16 gate preacts [t][R][w][lane][16] = 262MB
#define GXEE_US   ((size_t)(T_TOTAL+1)*16*8*64*8)   // f16 E tiles      [t][R][w][lane][8]  = 131MB
#define WPACK_US  (8u*6u*8u*64u*8u)                 // recurrent-weight B-fragments (f16 bits)
#define WXPACK_US (48u*3u*64u*8u)                   // x-weight B-fragments (K padded 85->96)

__device__ __forceinline__ unsigned short f2h(float f){
  _Float16 h = (_Float16)f;
  return __builtin_bit_cast(unsigned short, h);
}

// ---------------- k0: pack weights into MFMA B-fragment order (f16) ----------------
// wpack[w(8)][tile(6: r0,r1,u0,u1,c0,c1)][kt(8)][lane(64)][j(8)]
//   tau = 2w + (tile&1); value = W[k = kt*32 + (l>>4)*8 + j][col = 16*tau + (l&15)]
__global__ void k0_pack(const float* __restrict__ gk, const float* __restrict__ ck,
                        unsigned short* __restrict__ wpack, unsigned short* __restrict__ wxpack){
  int tid = blockIdx.x*256 + threadIdx.x;
  if (tid < (int)WPACK_US) {
    int j = tid & 7, l = (tid >> 3) & 63, kt = (tid >> 9) & 7, wt = tid >> 12;
    int w = wt / 6, tile = wt - 6*w;
    int lrow = l & 15, lquad = l >> 4;
    int k = kt*32 + lquad*8 + j;            // hidden index 0..255
    int tau = 2*w + (tile & 1);             // n-tile 0..15
    int kind = tile >> 1;                   // 0=r, 1=u, 2=c
    float v;
    if (kind == 0)      v = gk[(size_t)(85 + k)*512 + 16*tau + lrow];
    else if (kind == 1) v = gk[(size_t)(85 + k)*512 + 256 + 16*tau + lrow];
    else                v = ck[(size_t)(85 + k)*256 + 16*tau + lrow];
    wpack[tid] = f2h(v);
  } else if (tid < (int)(WPACK_US + WXPACK_US)) {
    int f = tid - (int)WPACK_US;
    int j = f & 7, l = (f >> 3) & 63, r = f >> 9;   // r = tau*3 + kt
    int kt = r % 3, tau = r / 3;
    int lrow = l & 15, lquad = l >> 4;
    int k = kt*32 + lquad*8 + j;            // x index, pad >=85 -> 0
    float v = 0.0f;
    if (k < NIN) {
      if (tau < 32) v = gk[(size_t)k*512 + 16*tau + lrow];
      else          v = ck[(size_t)k*256 + 16*(tau-32) + lrow];
    }
    wxpack[f] = f2h(v);
  }
}

// ---------------- k1: gxe precompute, ONE dispatch over all T ----------------
// gates (tau<32): kind=tau>>4 (0=r,1=u), w=(tau&15)>>1, p=tau&1
//   -> f16 gxeG[t][R][w][lane][kind*8 + p*4 + i]
// E (tau>=32, e=tau-32): -> f16 gxeE[t][R][e>>1][lane][(e&1)*4 + i]
__global__ __launch_bounds__(256) void k1_gxe(const float* __restrict__ x, const float* __restrict__ nz,
                       const float* __restrict__ gb, const float* __restrict__ cb,
                       const unsigned short* __restrict__ wxpack,
                       unsigned short* __restrict__ gxeG, unsigned short* __restrict__ gxeE){
  int R  = blockIdx.x;
  int t  = blockIdx.y;
  int tid = threadIdx.x;
  __shared__ _Float16 xA[16][104];           // 96 K (padded) + 8 pad
  {
    int r = tid >> 4, c0 = tid & 15;
    const float* xrow = x + ((size_t)t*BATCH + 16*R + r)*NIN;
    for (int c = c0; c < 96; c += 16)
      xA[r][c] = (_Float16)(c < NIN ? xrow[c] : 0.0f);
  }
  __syncthreads();
  int l = tid & 63, wv = tid >> 6;
  int lrow = l & 15, lquad = l >> 4;
  const half8* xA8 = (const half8*)xA;       // row stride 104 f16 = 13 half8
  half8 afr[3];
  #pragma unroll
  for (int kt = 0; kt < 3; ++kt)
    afr[kt] = xA8[lrow*13 + kt*4 + lquad];
  const half8* wx8 = (const half8*)wxpack;
  for (int u = 0; u < 12; ++u) {
    int tau = wv + 4*u;                      // balanced: each wave gets 4 cand tiles
    f32x4 acc;
    if (tau < 32) {
      float b = gb[16*tau + lrow];
      acc = (f32x4){b, b, b, b};
    } else {
      int nc = 16*(tau-32) + lrow;
      float b = cb[nc];
      #pragma unroll
      for (int i = 0; i < 4; ++i)
        acc[i] = fmaf(SIGMA_C, nz[((size_t)t*BATCH + 16*R + lquad*4 + i)*NH + nc], b);
    }
    #pragma unroll
    for (int kt = 0; kt < 3; ++kt)
      acc = __builtin_amdgcn_mfma_f32_16x16x32_f16(afr[kt], wx8[((size_t)tau*3 + kt)*64 + l], acc, 0, 0, 0);
    half4 o = {(_Float16)acc[0], (_Float16)acc[1], (_Float16)acc[2], (_Float16)acc[3]};
    if (tau < 32) {
      int kind = tau >> 4, w2 = (tau & 15) >> 1, p = tau & 1;
      *(half4*)(gxeG + ((((size_t)t*16 + R)*8 + w2)*64 + (size_t)l)*16 + kind*8 + p*4) = o;
    } else {
      int e = tau - 32, w2 = e >> 1, p = e & 1;
      *(half4*)(gxeE + ((((size_t)t*16 + R)*8 + w2)*64 + (size_t)l)*8 + p*4) = o;
    }
  }
}

// ---------------- k2: ONE persistent recurrent scan over all 1000 steps ----------------
// 16 WGs x 8 waves (2 waves/SIMD). WG R owns rows [16R,16R+16); wave w owns cols [32w,32w+32).
// cand = cx + (r .* h) @ Wc_h + sigma*n  (r applied BEFORE the matmul).
// Champion configuration (R10): gate preacts & E go straight HBM->VGPR (f16, double-
// buffered one step ahead) — no LDS-DMA, no asm ds_reads, no counted-vmcnt machinery.
// Plain MFMA intrinsics (compiler-managed hazards; AGPR-homed srcB reads directly).
// Sync: exactly 2x (s_waitcnt lgkmcnt(0); s_barrier) per step; out stores never drain.
__global__ __launch_bounds__(512, 2) void k2_rec(const float* __restrict__ hin,
                       const unsigned short* __restrict__ wpack,
                       const unsigned short* __restrict__ gG,
                       const unsigned short* __restrict__ gE,
                       float* __restrict__ out){
  int R = blockIdx.x;
  int tid = threadIdx.x;
  int l = tid & 63, w = tid >> 6;
  int lrow = l & 15, lquad = l >> 4;

  __shared__ _Float16 hA[16][264];           // h f16  [row][n], stride 264
  __shared__ _Float16 rhA[16][264];          // r.*h f16, same layout

  { // init hA
    int r = tid >> 5, c0 = (tid & 31)*8;
    const float* hrow = hin + ((size_t)(16*R + r))*NH + c0;
    #pragma unroll
    for (int i = 0; i < 8; ++i)
      hA[r][c0+i] = (_Float16)hrow[i];
  }
  float hreg[2][4];                          // h f32, lane-private (rows lquad*4+i, cols 32w+16p+lrow)
  #pragma unroll
  for (int p = 0; p < 2; ++p)
    #pragma unroll
    for (int i = 0; i < 4; ++i)
      hreg[p][i] = hin[(size_t)(16*R + lquad*4 + i)*NH + 32*w + 16*p + lrow];

  // resident weight fragments (192 regs; compiler splits arch/AGPR)
  half8 wf[6][8];
  const half8* wp8 = (const half8*)wpack;
  #pragma unroll
  for (int tile = 0; tile < 6; ++tile)
    #pragma unroll
    for (int kt = 0; kt < 8; ++kt)
      wf[tile][kt] = wp8[((w*6 + tile)*8 + kt)*64 + l];

  // gate / E streams: per-lane 32B (gates) + 16B (E) per step, f16
  const half8* gg  = (const half8*)gG + (((size_t)R*8 + w)*64 + (size_t)l)*2;
  const size_t gstepG = (size_t)16*8*64*2;   // half8 units per time step
  const half8* gep = (const half8*)gE + (((size_t)R*8 + w)*64 + (size_t)l);
  const size_t estep = (size_t)16*8*64;      // half8 units per time step

  half8 g0 = gg[0], g1 = gg[1];  gg += gstepG;   // gates(0): [r p0..p1 | u p0..p1]
  half8 eh = gep[0];             gep += estep;   // E(0)
  __syncthreads();

  const half8* hA8  = (const half8*)hA;      // row stride 33 half8
  const half8* rhA8 = (const half8*)rhA;
  float* outp = out + ((size_t)(16*R + lquad*4))*NH + 32*w + lrow;

  for (int t = 0; t < T_TOTAL; ++t) {
    // acc init from prefetched gates (lane-private, no LDS)
    f32x4 accr[2], accu[2];
    #pragma unroll
    for (int p = 0; p < 2; ++p)
      #pragma unroll
      for (int i = 0; i < 4; ++i){
        accr[p][i] = (float)g0[p*4 + i];
        accu[p][i] = (float)g1[p*4 + i];
      }
    // prefetch gates(t+1) (slack slab at t=999); ~full step covers HBM latency
    g0 = gg[0]; g1 = gg[1]; gg += gstepG;
    // phase A: h @ Wg_h  (tiles r0,r1,u0,u1)
    #pragma unroll
    for (int kt = 0; kt < 8; ++kt){
      half8 af = hA8[lrow*33 + kt*4 + lquad];
      #pragma unroll
      for (int p = 0; p < 2; ++p){
        accr[p] = __builtin_amdgcn_mfma_f32_16x16x32_f16(af, wf[p  ][kt], accr[p], 0, 0, 0);
        accu[p] = __builtin_amdgcn_mfma_f32_16x16x32_f16(af, wf[2+p][kt], accu[p], 0, 0, 0);
      }
    }
    // ew1: u-gates -> packed f16 aug; r-gates -> rhA
    half4 haug[2];
    #pragma unroll
    for (int p = 0; p < 2; ++p)
      #pragma unroll
      for (int i = 0; i < 4; ++i){
        float eu = __expf(-accu[p][i]);
        haug[p][i] = (_Float16)(ALPHA_C * __builtin_amdgcn_rcpf(1.0f + eu));
      }
    #pragma unroll
    for (int p = 0; p < 2; ++p){
      int ncol = 32*w + 16*p + lrow;
      #pragma unroll
      for (int i = 0; i < 4; ++i){
        float er = __expf(-accr[p][i]);
        float rg = __builtin_amdgcn_rcpf(1.0f + er);
        rhA[lquad*4+i][ncol] = (_Float16)(rg * hreg[p][i]);
      }
    }
    asm volatile("s_waitcnt lgkmcnt(0)\n\ts_barrier" ::: "memory");  // rhA visible
    // phase B: (r.*h) @ Wc_h  (tiles c0,c1)
    f32x4 accB[2];
    accB[0] = (f32x4){0.f,0.f,0.f,0.f};
    accB[1] = (f32x4){0.f,0.f,0.f,0.f};
    #pragma unroll
    for (int kt = 0; kt < 8; ++kt){
      half8 af = rhA8[lrow*33 + kt*4 + lquad];
      #pragma unroll
      for (int p = 0; p < 2; ++p)
        accB[p] = __builtin_amdgcn_mfma_f32_16x16x32_f16(af, wf[4+p][kt], accB[p], 0, 0, 0);
    }
    // ew2: cand -> tanh -> leaky update; publish new h; 8 out stores (never drained)
    #pragma unroll
    for (int p = 0; p < 2; ++p){
      int ncol = 32*w + 16*p + lrow;
      #pragma unroll
      for (int i = 0; i < 4; ++i){
        float cand = accB[p][i] + (float)eh[p*4 + i];
        float e2 = __expf(2.0f*cand);
        float c  = (e2 - 1.0f)*__builtin_amdgcn_rcpf(e2 + 1.0f);
        float hold = hreg[p][i];
        float hnew = fmaf((float)haug[p][i], c - hold, hold);
        hreg[p][i] = hnew;
        hA[lquad*4+i][ncol] = (_Float16)hnew;
        outp[(size_t)i*NH + (size_t)p*16] = hnew;
      }
    }
    outp += (size_t)BATCH*NH;
    // prefetch E(t+1) after last use of eh
    eh = gep[0]; gep += estep;
    asm volatile("s_waitcnt lgkmcnt(0)\n\ts_barrier" ::: "memory");  // hA visible
  }
}

extern "C" void kernel_launch(void* const* d_in, const int* in_sizes, int n_in,
                              void* d_out, int out_size, void* d_ws, size_t ws_size,
                              hipStream_t stream) {
  (void)in_sizes; (void)n_in; (void)out_size; (void)ws_size;
  const float* x  = (const float*)d_in[0];
  const float* h0 = (const float*)d_in[1];
  const float* gk = (const float*)d_in[2];
  const float* gb = (const float*)d_in[3];
  const float* ck = (const float*)d_in[4];
  const float* cb = (const float*)d_in[5];
  const float* nz = (const float*)d_in[6];
  float* out = (float*)d_out;

  unsigned short* gxeG   = (unsigned short*)d_ws;           // 262MB f16 gates
  unsigned short* gxeE   = gxeG + GXEG_US;                  // 131MB f16 E
  unsigned short* wpack  = gxeE + GXEE_US;
  unsigned short* wxpack = wpack + WPACK_US;

  k0_pack<<<1056, 256, 0, stream>>>(gk, ck, wpack, wxpack);
  k1_gxe<<<dim3(16, T_TOTAL), 256, 0, stream>>>(x, nz, gb, cb, wxpack, gxeG, gxeE);
  k2_rec<<<16, 512, 0, stream>>>(h0, wpack, gxeG, gxeE, out);
}